// Round 12
// baseline (1446.194 us; speedup 1.0000x reference)
//
#include <hip/hip_runtime.h>
#include <math.h>

#define L_ 6
#define H_ 6
#define HS_ 64
#define D_ 384
#define T_ 256
#define V_ 65
#define B_ 64
#define ROWS (B_*T_)        // 16384
#define QKVN 1152
#define EPS_ 1e-5f

typedef __attribute__((ext_vector_type(8))) __bf16 bf16x8;
typedef __attribute__((ext_vector_type(2))) __bf16 bf16x2;
typedef __attribute__((ext_vector_type(4))) float f32x4;

__device__ __forceinline__ bf16x8 u4_to_bf8(uint4 u) {
    return __builtin_bit_cast(bf16x8, u);
}

// async global->LDS, 16B per lane. lds ptr wave-uniform; HW scatters lane i to lds + i*16.
__device__ __forceinline__ void glds16(const void* g, void* l) {
    __builtin_amdgcn_global_load_lds(
        (const __attribute__((address_space(1))) void*)g,
        (__attribute__((address_space(3))) void*)l, 16, 0, 0);
}

// ---------------------------------------------------------------- embedding
__global__ __launch_bounds__(256)
void embed_kernel(const int* __restrict__ idx,
                  const float* __restrict__ tok,
                  const float* __restrict__ pos,
                  float* __restrict__ x) {
    int i = blockIdx.x * blockDim.x + threadIdx.x;   // < ROWS*D_/4
    int e = i * 4;
    int d = e % D_;
    int row = e / D_;
    int t = row % T_;
    const float4 tv = *(const float4*)(tok + (size_t)idx[row]*D_ + d);
    const float4 pv = *(const float4*)(pos + (size_t)t*D_ + d);
    float4 r;
    r.x = tv.x + pv.x; r.y = tv.y + pv.y;
    r.z = tv.z + pv.z; r.w = tv.w + pv.w;
    *(float4*)(x + e) = r;
}

// ---------------------------------------------------------------- layernorm
__global__ __launch_bounds__(256)
void ln4(const float* __restrict__ x,
         const float* __restrict__ g,
         const float* __restrict__ b,
         __bf16* __restrict__ yb) {
    int w = threadIdx.x >> 6, lane = threadIdx.x & 63;
    int row = blockIdx.x * 4 + w;
    const float* xr = x + (size_t)row * D_;
    float2 v[3];
    #pragma unroll
    for (int i = 0; i < 3; ++i) v[i] = *(const float2*)(xr + lane*2 + 128*i);
    float s = 0.f, sq = 0.f;
    #pragma unroll
    for (int i = 0; i < 3; ++i) {
        s += v[i].x + v[i].y;
        sq += v[i].x*v[i].x + v[i].y*v[i].y;
    }
    for (int off = 32; off; off >>= 1) {
        s  += __shfl_xor(s,  off);
        sq += __shfl_xor(sq, off);
    }
    float mean = s * (1.0f/D_);
    float var  = sq * (1.0f/D_) - mean*mean;
    float rstd = rsqrtf(var + EPS_);
    __bf16* yr = yb + (size_t)row * D_;
    #pragma unroll
    for (int i = 0; i < 3; ++i) {
        int c = lane*2 + 128*i;
        float2 gv = *(const float2*)(g + c);
        float2 bv = *(const float2*)(b + c);
        bf16x2 pr;
        pr[0] = (__bf16)((v[i].x-mean)*rstd*gv.x + bv.x);
        pr[1] = (__bf16)((v[i].y-mean)*rstd*gv.y + bv.y);
        *(bf16x2*)(yr + c) = pr;
    }
}

// ---------------------------------------------------------------- transpose+cast
__global__ __launch_bounds__(256)
void transpose_cast(const float* __restrict__ src, __bf16* __restrict__ dst,
                    int R, int C, int zdiv, long sA, long sB, long dbase)
{
    __shared__ float tile[32][33];
    int z = blockIdx.z;
    const float* s = src + (long)z * R * C;
    __bf16* d = dst + dbase + (long)(z / zdiv) * sA + (long)(z % zdiv) * sB;
    int c0 = blockIdx.x * 32, r0 = blockIdx.y * 32;
    int t = threadIdx.x;
    int tr = t >> 3, tc = (t & 7) * 4;
    float4 v = *(const float4*)(s + (long)(r0 + tr) * C + c0 + tc);
    tile[tr][tc+0] = v.x; tile[tr][tc+1] = v.y;
    tile[tr][tc+2] = v.z; tile[tr][tc+3] = v.w;
    __syncthreads();
    #pragma unroll
    for (int j = 0; j < 4; ++j)
        d[(long)(c0 + tr) * R + r0 + tc + j] = (__bf16)tile[tc+j][tr];
}

// head weight: Whead [384][65] fp32 -> headT [128][384] bf16 (zero-padded rows 65..127)
__global__ __launch_bounds__(256)
void head_prep(const float* __restrict__ Whead, __bf16* __restrict__ headT) {
    int i = blockIdx.x * 256 + threadIdx.x;   // < 128*384
    int n = i / D_, k = i % D_;
    headT[i] = (n < V_) ? (__bf16)Whead[k*V_ + n] : (__bf16)0.0f;
}

// ---------------------------------------------------------------- TM=64 BK=64 GEMM (proj/FFN2/head)
// Field-proven (R10/R11, refcheck-passed). BK=64 staging (128 B/row granule),
// 2-buf 48 KB LDS -> 3 blk/CU. Staged-byte model: dur = M*N*K*2*(1/64+1/128) / 7.6 TB/s.
__global__ __launch_bounds__(256)
void gemm64b(const __bf16* __restrict__ A, const __bf16* __restrict__ Bt,
             const float* __restrict__ bias, const float* res,
             float* outF, __bf16* outB,
             int K, int ldc, int ncols, int relu)
{
    __shared__ __align__(16) __bf16 As[2][64*64];     // 16 KB
    __shared__ __align__(16) __bf16 Bs[2][128*64];    // 32 KB
    int t = threadIdx.x;
    int w = t >> 6, lane = t & 63;
    int ln = lane & 15, quad = lane >> 4;
    int m0 = blockIdx.x * 64, n0 = blockIdx.y * 128;
    int wm = (w >> 1) * 32, wn = (w & 1) * 64;

    f32x4 acc[2][4] = {};

    const char* Ab = (const char*)A + (size_t)m0 * K * 2;
    const char* Bb = (const char*)Bt + (size_t)n0 * K * 2;
    int fb = w*64 + lane;
    size_t gaA[2]; int loA[2];
    #pragma unroll
    for (int ra = 0; ra < 2; ++ra) {
        int f = fb + 256*ra;
        gaA[ra] = (size_t)(f >> 3) * (K*2) + (size_t)(((f & 7) ^ ((f >> 3) & 7)) * 16);
        loA[ra] = (w*64 + 256*ra) * 16;      // wave-uniform LDS base
    }
    size_t gaB[4]; int loB[4];
    #pragma unroll
    for (int rb = 0; rb < 4; ++rb) {
        int f = fb + 256*rb;
        gaB[rb] = (size_t)(f >> 3) * (K*2) + (size_t)(((f & 7) ^ ((f >> 3) & 7)) * 16);
        loB[rb] = (w*64 + 256*rb) * 16;      // wave-uniform LDS base
    }

    int nIt = K >> 6;

    #define STAGE64B(buf, itv) do {                                        \
        size_t kb_ = (size_t)(itv) * 128;                                  \
        _Pragma("unroll")                                                  \
        for (int ra = 0; ra < 2; ++ra)                                     \
            glds16(Ab + gaA[ra] + kb_, (char*)As[buf] + loA[ra]);          \
        _Pragma("unroll")                                                  \
        for (int rb = 0; rb < 4; ++rb)                                     \
            glds16(Bb + gaB[rb] + kb_, (char*)Bs[buf] + loB[rb]);          \
    } while (0)

    STAGE64B(0, 0);

    for (int it = 0; it < nIt; ++it) {
        int p = it & 1;
        __syncthreads();               // staging of buf p complete; reads of p^1 retired
        if (it + 1 < nIt)
            STAGE64B(p^1, it + 1);
        bf16x8 af[2][2], bfr[4][2];
        #pragma unroll
        for (int i = 0; i < 2; ++i) {
            int row = wm + i*16 + ln;
            #pragma unroll
            for (int kk = 0; kk < 2; ++kk)
                af[i][kk] = __builtin_bit_cast(bf16x8,
                    *(const uint4*)&As[p][row*64 + (((kk*4 + quad) ^ (row & 7)) * 8)]);
        }
        #pragma unroll
        for (int j = 0; j < 4; ++j) {
            int row = wn + j*16 + ln;
            #pragma unroll
            for (int kk = 0; kk < 2; ++kk)
                bfr[j][kk] = __builtin_bit_cast(bf16x8,
                    *(const uint4*)&Bs[p][row*64 + (((kk*4 + quad) ^ (row & 7)) * 8)]);
        }
        #pragma unroll
        for (int kk = 0; kk < 2; ++kk)
            #pragma unroll
            for (int i = 0; i < 2; ++i)
                #pragma unroll
                for (int j = 0; j < 4; ++j)
                    acc[i][j] = __builtin_amdgcn_mfma_f32_16x16x32_bf16(
                                    af[i][kk], bfr[j][kk], acc[i][j], 0, 0, 0);
    }
    #undef STAGE64B

    #pragma unroll
    for (int i = 0; i < 2; ++i) {
        #pragma unroll
        for (int r = 0; r < 4; ++r) {
            int row = m0 + wm + i*16 + quad*4 + r;
            #pragma unroll
            for (int j = 0; j < 4; ++j) {
                int col = n0 + wn + j*16 + ln;
                if (col < ncols) {
                    float v = acc[i][j][r];
                    if (bias) v += bias[col];
                    if (relu) v = fmaxf(v, 0.f);
                    if (res)  v += res[(size_t)row*ldc + col];
                    if (outF) outF[(size_t)row*ldc + col] = v;
                    if (outB) outB[(size_t)row*ldc + col] = (__bf16)v;
                }
            }
        }
    }
}

// ---------------------------------------------------------------- TM=128 BK=64 GEMM (QKV/FFN1)
// Staged-byte reduction: amplification (1/TM+1/TN) drops 0.0234 -> 0.0156 (-33% bytes)
// at the SAME proven BK=64 granule (7.6 TB/s measured). 64 KB LDS -> 2 blk/CU; in-flight
// staging/CU = 8 waves x 8 KB = 64 KB ~= the 3-block TM=64 case, so rate should hold.
// Only for GEMMs with N >= 1152 (grid stays >= 4.5 blocks/CU). Same swizzle (rows 0..127,
// row&7 XOR), same single-barrier 2-buf loop — pure parameter extension of gemm64b.
__global__ __launch_bounds__(256)
void gemm128b(const __bf16* __restrict__ A, const __bf16* __restrict__ Bt,
              const float* __restrict__ bias,
              float* outF, __bf16* outB,
              int K, int ldc, int ncols, int relu)
{
    __shared__ __align__(16) __bf16 As[2][128*64];    // 32 KB
    __shared__ __align__(16) __bf16 Bs[2][128*64];    // 32 KB
    int t = threadIdx.x;
    int w = t >> 6, lane = t & 63;
    int ln = lane & 15, quad = lane >> 4;
    int m0 = blockIdx.x * 128, n0 = blockIdx.y * 128;
    int wm = (w >> 1) * 64, wn = (w & 1) * 64;

    f32x4 acc[4][4] = {};

    const char* Ab = (const char*)A + (size_t)m0 * K * 2;
    const char* Bb = (const char*)Bt + (size_t)n0 * K * 2;
    int fb = w*64 + lane;
    size_t gaA[4]; int loA[4];
    #pragma unroll
    for (int ra = 0; ra < 4; ++ra) {
        int f = fb + 256*ra;            // f in [0,1024): rows 0..127, chunks 0..7
        gaA[ra] = (size_t)(f >> 3) * (K*2) + (size_t)(((f & 7) ^ ((f >> 3) & 7)) * 16);
        loA[ra] = (w*64 + 256*ra) * 16; // wave-uniform LDS base
    }
    size_t gaB[4]; int loB[4];
    #pragma unroll
    for (int rb = 0; rb < 4; ++rb) {
        int f = fb + 256*rb;
        gaB[rb] = (size_t)(f >> 3) * (K*2) + (size_t)(((f & 7) ^ ((f >> 3) & 7)) * 16);
        loB[rb] = (w*64 + 256*rb) * 16;
    }

    int nIt = K >> 6;   // K=384 -> 6

    #define STAGE128B(buf, itv) do {                                       \
        size_t kb_ = (size_t)(itv) * 128;                                  \
        _Pragma("unroll")                                                  \
        for (int ra = 0; ra < 4; ++ra)                                     \
            glds16(Ab + gaA[ra] + kb_, (char*)As[buf] + loA[ra]);          \
        _Pragma("unroll")                                                  \
        for (int rb = 0; rb < 4; ++rb)                                     \
            glds16(Bb + gaB[rb] + kb_, (char*)Bs[buf] + loB[rb]);          \
    } while (0)

    STAGE128B(0, 0);

    for (int it = 0; it < nIt; ++it) {
        int p = it & 1;
        __syncthreads();               // staging of buf p complete; reads of p^1 retired
        if (it + 1 < nIt)
            STAGE128B(p^1, it + 1);
        bf16x8 af[4][2], bfr[4][2];
        #pragma unroll
        for (int i = 0; i < 4; ++i) {
            int row = wm + i*16 + ln;
            #pragma unroll
            for (int kk = 0; kk < 2; ++kk)
                af[i][kk] = __builtin_bit_cast(bf16x8,
                    *(const uint4*)&As[p][row*64 + (((kk*4 + quad) ^ (row & 7)) * 8)]);
        }
        #pragma unroll
        for (int j = 0; j < 4; ++j) {
            int row = wn + j*16 + ln;
            #pragma unroll
            for (int kk = 0; kk < 2; ++kk)
                bfr[j][kk] = __builtin_bit_cast(bf16x8,
                    *(const uint4*)&Bs[p][row*64 + (((kk*4 + quad) ^ (row & 7)) * 8)]);
        }
        #pragma unroll
        for (int kk = 0; kk < 2; ++kk)
            #pragma unroll
            for (int i = 0; i < 4; ++i)
                #pragma unroll
                for (int j = 0; j < 4; ++j)
                    acc[i][j] = __builtin_amdgcn_mfma_f32_16x16x32_bf16(
                                    af[i][kk], bfr[j][kk], acc[i][j], 0, 0, 0);
    }
    #undef STAGE128B

    #pragma unroll
    for (int i = 0; i < 4; ++i) {
        #pragma unroll
        for (int r = 0; r < 4; ++r) {
            int row = m0 + wm + i*16 + quad*4 + r;
            #pragma unroll
            for (int j = 0; j < 4; ++j) {
                int col = n0 + wn + j*16 + ln;
                if (col < ncols) {
                    float v = acc[i][j][r];
                    if (bias) v += bias[col];
                    if (relu) v = fmaxf(v, 0.f);
                    if (outF) outF[(size_t)row*ldc + col] = v;
                    if (outB) outB[(size_t)row*ldc + col] = (__bf16)v;
                }
            }
        }
    }
}

// ---------------------------------------------------------------- MFMA flash attention
__global__ __launch_bounds__(256, 2)
void attn4(const __bf16* __restrict__ qkv, __bf16* __restrict__ o)
{
    __shared__ __align__(16) __bf16 Ks[256*72];
    __shared__ __align__(16) __bf16 Vt[64*264];
    __shared__ __align__(16) __bf16 Pw[4][32*40];
    int bid = blockIdx.x;
    int h = bid % H_;
    int b = bid / H_;
    int t = threadIdx.x;
    int w = t >> 6, lane = t & 63;
    int ln = lane & 15, quad = lane >> 4;
    const size_t rowb = (size_t)b * T_ * QKVN;
    const int hoff = h * HS_;
    const float scale = 0.05103103630798288f;   // 1/sqrt(384)

    for (int c = t; c < 2048; c += 256) {
        int r = c >> 3, e0 = (c & 7) * 8;
        uint4 uk = *(const uint4*)(qkv + rowb + (size_t)r*QKVN + 384 + hoff + e0);
        *(uint4*)&Ks[r*72 + e0] = uk;
        uint4 uv = *(const uint4*)(qkv + rowb + (size_t)r*QKVN + 768 + hoff + e0);
        bf16x8 v8 = u4_to_bf8(uv);
        #pragma unroll
        for (int j = 0; j < 8; ++j) {
            int e = e0 + j;
            Vt[e*264 + (((r >> 3) ^ ((e >> 3) & 3)) * 8) + (r & 7)] = v8[j];
        }
    }

    int qis[2] = { w, 7 - w };
    uint4 Qf[2][2][2];
    #pragma unroll
    for (int tl = 0; tl < 2; ++tl)
        #pragma unroll
        for (int mi = 0; mi < 2; ++mi)
            #pragma unroll
            for (int kc = 0; kc < 2; ++kc)
                Qf[tl][mi][kc] = *(const uint4*)(qkv + rowb +
                    (size_t)(qis[tl]*32 + mi*16 + ln)*QKVN + hoff + kc*32 + quad*8);

    __syncthreads();

    __bf16* P = Pw[w];
    #pragma unroll
    for (int tl = 0; tl < 2; ++tl) {
        int qi = qis[tl];
        f32x4 O[2][4] = {};
        float mst[2][4], lst[2][4];
        #pragma unroll
        for (int mi = 0; mi < 2; ++mi)
            #pragma unroll
            for (int r = 0; r < 4; ++r) { mst[mi][r] = -INFINITY; lst[mi][r] = 0.f; }

        for (int st = 0; st <= qi; ++st) {
            int sb = st * 32;
            f32x4 S[2][2] = {};
            #pragma unroll
            for (int kc = 0; kc < 2; ++kc) {
                uint4 Kf[2];
                #pragma unroll
                for (int ji = 0; ji < 2; ++ji)
                    Kf[ji] = *(const uint4*)&Ks[(sb + ji*16 + ln)*72 + kc*32 + quad*8];
                __builtin_amdgcn_s_setprio(1);
                #pragma unroll
                for (int mi = 0; mi < 2; ++mi) {
                    bf16x8 qa = __builtin_bit_cast(bf16x8, Qf[tl][mi][kc]);
                    #pragma unroll
                    for (int ji = 0; ji < 2; ++ji)
                        S[mi][ji] = __builtin_amdgcn_mfma_f32_16x16x32_bf16(
                            qa, __builtin_bit_cast(bf16x8, Kf[ji]), S[mi][ji], 0, 0, 0);
                }
                __builtin_amdgcn_s_setprio(0);
            }
            int diag = (st == qi);
            #pragma unroll
            for (int mi = 0; mi < 2; ++mi)
                #pragma unroll
                for (int ji = 0; ji < 2; ++ji)
                    #pragma unroll
                    for (int r = 0; r < 4; ++r) {
                        float v = S[mi][ji][r] * scale;
                        if (diag && (ji*16 + ln) > (mi*16 + quad*4 + r)) v = -INFINITY;
                        S[mi][ji][r] = v;
                    }
            #pragma unroll
            for (int mi = 0; mi < 2; ++mi)
                #pragma unroll
                for (int r = 0; r < 4; ++r) {
                    float mx = fmaxf(S[mi][0][r], S[mi][1][r]);
                    #pragma unroll
                    for (int off = 1; off < 16; off <<= 1)
                        mx = fmaxf(mx, __shfl_xor(mx, off));
                    float mn = fmaxf(mst[mi][r], mx);
                    float al = __expf(mst[mi][r] - mn);
                    mst[mi][r] = mn;
                    float p0 = __expf(S[mi][0][r] - mn);
                    float p1 = __expf(S[mi][1][r] - mn);
                    S[mi][0][r] = p0; S[mi][1][r] = p1;
                    float rs = p0 + p1;
                    #pragma unroll
                    for (int off = 1; off < 16; off <<= 1)
                        rs += __shfl_xor(rs, off);
                    lst[mi][r] = lst[mi][r]*al + rs;
                    #pragma unroll
                    for (int ei = 0; ei < 4; ++ei) O[mi][ei][r] *= al;
                }
            #pragma unroll
            for (int mi = 0; mi < 2; ++mi)
                #pragma unroll
                for (int ji = 0; ji < 2; ++ji)
                    #pragma unroll
                    for (int r = 0; r < 4; ++r)
                        P[(mi*16 + quad*4 + r)*40 + ji*16 + ln] = (__bf16)S[mi][ji][r];
            uint4 Pf[2], Vf[4];
            #pragma unroll
            for (int mi = 0; mi < 2; ++mi)
                Pf[mi] = *(const uint4*)&P[(mi*16 + ln)*40 + quad*8];
            #pragma unroll
            for (int ei = 0; ei < 4; ++ei) {
                int e = ei*16 + ln;
                Vf[ei] = *(const uint4*)&Vt[e*264 + (((st*4 + quad) ^ ((e >> 3) & 3)) * 8)];
            }
            __builtin_amdgcn_s_setprio(1);
            #pragma unroll
            for (int mi = 0; mi < 2; ++mi)
                #pragma unroll
                for (int ei = 0; ei < 4; ++ei)
                    O[mi][ei] = __builtin_amdgcn_mfma_f32_16x16x32_bf16(
                        __builtin_bit_cast(bf16x8, Pf[mi]),
                        __builtin_bit_cast(bf16x8, Vf[ei]), O[mi][ei], 0, 0, 0);
            __builtin_amdgcn_s_setprio(0);
        }
        #pragma unroll
        for (int mi = 0; mi < 2; ++mi)
            #pragma unroll
            for (int r = 0; r < 4; ++r) {
                float inv = 1.0f / lst[mi][r];
                size_t row = (size_t)(b*T_ + qi*32 + mi*16 + quad*4 + r);
                #pragma unroll
                for (int ei = 0; ei < 4; ++ei)
                    o[row*D_ + hoff + ei*16 + ln] = (__bf16)(O[mi][ei][r] * inv);
            }
    }
}

// ---------------------------------------------------------------- loss
__global__ __launch_bounds__(256)
void loss2(const float* __restrict__ logits,
           const int* __restrict__ tg,
           float* __restrict__ loss)
{
    int t = threadIdx.x;
    int g16 = t >> 4, ln = t & 15;
    int row = blockIdx.x * 16 + g16;
    const float* lr = logits + (size_t)row * V_;
    float v0 = lr[ln], v1 = lr[16+ln], v2 = lr[32+ln], v3 = lr[48+ln];
    float v4 = (ln == 0) ? lr[64] : -INFINITY;
    float m = fmaxf(fmaxf(fmaxf(v0, v1), fmaxf(v2, v3)), v4);
    #pragma unroll
    for (int off = 1; off < 16; off <<= 1) m = fmaxf(m, __shfl_xor(m, off));
    float s = __expf(v0-m) + __expf(v1-m) + __expf(v2-m) + __expf(v3-m);
    if (ln == 0) s += __expf(v4-m);
    #pragma unroll
    for (int off = 1; off < 16; off <<= 1) s += __shfl_xor(s, off);
    float val = 0.f;
    if (ln == 0)
        val = -(lr[tg[row]] - m - __logf(s)) * (1.0f/ROWS);
    #pragma unroll
    for (int off = 16; off < 64; off <<= 1) val += __shfl_xor(val, off);
    __shared__ float red[4];
    int w = t >> 6;
    if ((t & 63) == 0) red[w] = val;
    __syncthreads();
    if (t == 0)
        atomicAdd(loss, red[0]+red[1]+red[2]+red[3]);
}

// ---------------------------------------------------------------- launch
extern "C" void kernel_launch(void* const* d_in, const int* in_sizes, int n_in,
                              void* d_out, int out_size, void* d_ws, size_t ws_size,
                              hipStream_t stream)
{
    const int*   idx     = (const int*)  d_in[0];
    const int*   targets = (const int*)  d_in[1];
    const float* tok     = (const float*)d_in[2];
    const float* pos     = (const float*)d_in[3];
    const float* Wq      = (const float*)d_in[4];
    const float* Wk      = (const float*)d_in[5];
    const float* Wv      = (const float*)d_in[6];
    const float* Wproj   = (const float*)d_in[7];
    const float* bproj   = (const float*)d_in[8];
    const float* W1      = (const float*)d_in[9];
    const float* b1      = (const float*)d_in[10];
    const float* W2      = (const float*)d_in[11];
    const float* b2      = (const float*)d_in[12];
    const float* ln1g    = (const float*)d_in[13];
    const float* ln1b    = (const float*)d_in[14];
    const float* lnfg    = (const float*)d_in[15];
    const float* lnfb    = (const float*)d_in[16];
    const float* Whead   = (const float*)d_in[17];
    const float* bhead   = (const float*)d_in[18];

    float* logits = (float*)d_out;
    float* loss   = logits + (size_t)ROWS * V_;

    const size_t SZ = (size_t)ROWS * D_;             // 6291456
    const size_t RGELEMS = (size_t)ROWS * 4 * D_;    // 25165824 bf16 elems

    float*  x   = (float*)d_ws;                      // SZ f32
    __bf16* yb  = (__bf16*)(x + SZ);                 // SZ bf16
    __bf16* Rg  = yb + SZ;                           // RGELEMS bf16 (qkv / hid)
    __bf16* qkv = Rg;                                // ROWS*1152
    __bf16* hid = Rg;                                // ROWS*1536
    __bf16* o   = Rg + RGELEMS;                      // SZ bf16
    __bf16* qkvT  = o + SZ;                          // L*1152*384
    __bf16* projT = qkvT + (size_t)L_*QKVN*D_;       // L*384*384
    __bf16* w1T   = projT + (size_t)L_*D_*D_;        // L*1536*384
    __bf16* w2T   = w1T + (size_t)L_*D_*4*D_;        // L*384*1536
    __bf16* headT = w2T + (size_t)L_*D_*4*D_;        // 128*384

    // weight conversion (transpose to [N][K] bf16)
    transpose_cast<<<dim3(2,12,36),256,0,stream>>>(Wq, qkvT, D_, HS_, H_,
        (long)QKVN*D_, (long)HS_*D_, 0L);
    transpose_cast<<<dim3(2,12,36),256,0,stream>>>(Wk, qkvT, D_, HS_, H_,
        (long)QKVN*D_, (long)HS_*D_, (long)D_*D_);
    transpose_cast<<<dim3(2,12,36),256,0,stream>>>(Wv, qkvT, D_, HS_, H_,
        (long)QKVN*D_, (long)HS_*D_, 2L*D_*D_);
    transpose_cast<<<dim3(12,12,6),256,0,stream>>>(Wproj, projT, D_, D_, 1,
        (long)D_*D_, 0L, 0L);
    transpose_cast<<<dim3(48,12,6),256,0,stream>>>(W1, w1T, D_, 4*D_, 1,
        (long)D_*4*D_, 0L, 0L);
    transpose_cast<<<dim3(12,48,6),256,0,stream>>>(W2, w2T, 4*D_, D_, 1,
        (long)D_*4*D_, 0L, 0L);
    head_prep<<<(128*D_)/256, 256, 0, stream>>>(Whead, headT);

    embed_kernel<<<(ROWS*D_/4)/256, 256, 0, stream>>>(idx, tok, pos, x);

    for (int l = 0; l < L_; ++l) {
        ln4<<<ROWS/4, 256, 0, stream>>>(x, ln1g + l*D_, ln1b + l*D_, yb);
        gemm128b<<<dim3(ROWS/128, QKVN/128), 256, 0, stream>>>(
            yb, qkvT + (size_t)l*QKVN*D_, nullptr, nullptr, qkv,
            D_, QKVN, QKVN, 0);
        attn4<<<B_*H_, 256, 0, stream>>>(qkv, o);
        gemm64b<<<dim3(ROWS/64, D_/128), 256, 0, stream>>>(
            o, projT + (size_t)l*D_*D_, bproj + l*D_, x, x, nullptr,
            D_, D_, D_, 0);
        ln4<<<ROWS/4, 256, 0, stream>>>(x, ln1g + l*D_, ln1b + l*D_, yb);
        gemm128b<<<dim3(ROWS/128, 4*D_/128), 256, 0, stream>>>(
            yb, w1T + (size_t)l*D_*4*D_, b1 + l*4*D_, nullptr, hid,
            D_, 4*D_, 4*D_, 1);
        gemm64b<<<dim3(ROWS/64, D_/128), 256, 0, stream>>>(
            hid, w2T + (size_t)l*D_*4*D_, b2 + l*D_, x, x, nullptr,
            4*D_, D_, D_, 0);
    }
    ln4<<<ROWS/4, 256, 0, stream>>>(x, lnfg, lnfb, yb);
    gemm64b<<<dim3(ROWS/64, 1), 256, 0, stream>>>(
        yb, headT, bhead, nullptr, logits, nullptr,
        D_, V_, V_, 0);
    hipMemsetAsync(loss, 0, sizeof(float), stream);
    loss2<<<ROWS/16, 256, 0, stream>>>(logits, targets, loss);
}

// Round 13
// 1322.578 us; speedup vs baseline: 1.0935x; 1.0935x over previous
//
#include <hip/hip_runtime.h>
#include <math.h>

#define L_ 6
#define H_ 6
#define HS_ 64
#define D_ 384
#define T_ 256
#define V_ 65
#define B_ 64
#define ROWS (B_*T_)        // 16384
#define QKVN 1152
#define EPS_ 1e-5f

typedef __attribute__((ext_vector_type(8))) __bf16 bf16x8;
typedef __attribute__((ext_vector_type(2))) __bf16 bf16x2;
typedef __attribute__((ext_vector_type(4))) float f32x4;

__device__ __forceinline__ bf16x8 u4_to_bf8(uint4 u) {
    return __builtin_bit_cast(bf16x8, u);
}

// async global->LDS, 16B per lane. lds ptr wave-uniform; HW scatters lane i to lds + i*16.
__device__ __forceinline__ void glds16(const void* g, void* l) {
    __builtin_amdgcn_global_load_lds(
        (const __attribute__((address_space(1))) void*)g,
        (__attribute__((address_space(3))) void*)l, 16, 0, 0);
}

// ---------------------------------------------------------------- embedding
__global__ __launch_bounds__(256)
void embed_kernel(const int* __restrict__ idx,
                  const float* __restrict__ tok,
                  const float* __restrict__ pos,
                  float* __restrict__ x) {
    int i = blockIdx.x * blockDim.x + threadIdx.x;   // < ROWS*D_/4
    int e = i * 4;
    int d = e % D_;
    int row = e / D_;
    int t = row % T_;
    const float4 tv = *(const float4*)(tok + (size_t)idx[row]*D_ + d);
    const float4 pv = *(const float4*)(pos + (size_t)t*D_ + d);
    float4 r;
    r.x = tv.x + pv.x; r.y = tv.y + pv.y;
    r.z = tv.z + pv.z; r.w = tv.w + pv.w;
    *(float4*)(x + e) = r;
}

// ---------------------------------------------------------------- layernorm
__global__ __launch_bounds__(256)
void ln4(const float* __restrict__ x,
         const float* __restrict__ g,
         const float* __restrict__ b,
         __bf16* __restrict__ yb) {
    int w = threadIdx.x >> 6, lane = threadIdx.x & 63;
    int row = blockIdx.x * 4 + w;
    const float* xr = x + (size_t)row * D_;
    float2 v[3];
    #pragma unroll
    for (int i = 0; i < 3; ++i) v[i] = *(const float2*)(xr + lane*2 + 128*i);
    float s = 0.f, sq = 0.f;
    #pragma unroll
    for (int i = 0; i < 3; ++i) {
        s += v[i].x + v[i].y;
        sq += v[i].x*v[i].x + v[i].y*v[i].y;
    }
    for (int off = 32; off; off >>= 1) {
        s  += __shfl_xor(s,  off);
        sq += __shfl_xor(sq, off);
    }
    float mean = s * (1.0f/D_);
    float var  = sq * (1.0f/D_) - mean*mean;
    float rstd = rsqrtf(var + EPS_);
    __bf16* yr = yb + (size_t)row * D_;
    #pragma unroll
    for (int i = 0; i < 3; ++i) {
        int c = lane*2 + 128*i;
        float2 gv = *(const float2*)(g + c);
        float2 bv = *(const float2*)(b + c);
        bf16x2 pr;
        pr[0] = (__bf16)((v[i].x-mean)*rstd*gv.x + bv.x);
        pr[1] = (__bf16)((v[i].y-mean)*rstd*gv.y + bv.y);
        *(bf16x2*)(yr + c) = pr;
    }
}

// ---------------------------------------------------------------- transpose+cast
__global__ __launch_bounds__(256)
void transpose_cast(const float* __restrict__ src, __bf16* __restrict__ dst,
                    int R, int C, int zdiv, long sA, long sB, long dbase)
{
    __shared__ float tile[32][33];
    int z = blockIdx.z;
    const float* s = src + (long)z * R * C;
    __bf16* d = dst + dbase + (long)(z / zdiv) * sA + (long)(z % zdiv) * sB;
    int c0 = blockIdx.x * 32, r0 = blockIdx.y * 32;
    int t = threadIdx.x;
    int tr = t >> 3, tc = (t & 7) * 4;
    float4 v = *(const float4*)(s + (long)(r0 + tr) * C + c0 + tc);
    tile[tr][tc+0] = v.x; tile[tr][tc+1] = v.y;
    tile[tr][tc+2] = v.z; tile[tr][tc+3] = v.w;
    __syncthreads();
    #pragma unroll
    for (int j = 0; j < 4; ++j)
        d[(long)(c0 + tr) * R + r0 + tc + j] = (__bf16)tile[tc+j][tr];
}

// head weight: Whead [384][65] fp32 -> headT [128][384] bf16 (zero-padded rows 65..127)
__global__ __launch_bounds__(256)
void head_prep(const float* __restrict__ Whead, __bf16* __restrict__ headT) {
    int i = blockIdx.x * 256 + threadIdx.x;   // < 128*384
    int n = i / D_, k = i % D_;
    headT[i] = (n < V_) ? (__bf16)Whead[k*V_ + n] : (__bf16)0.0f;
}

// ---------------------------------------------------------------- TM=64 BK=64 GEMM (proj/FFN2/head)
// Field-proven (R10/R11). BK=64 granule, 2-buf 48 KB LDS -> 3 blk/CU -> ~7.6-8.8 TB/s
// staged-byte rate. Model: dur = M*N*K*2*(1/64+1/128) / rate.
__global__ __launch_bounds__(256)
void gemm64b(const __bf16* __restrict__ A, const __bf16* __restrict__ Bt,
             const float* __restrict__ bias, const float* res,
             float* outF, __bf16* outB,
             int K, int ldc, int ncols, int relu)
{
    __shared__ __align__(16) __bf16 As[2][64*64];     // 16 KB
    __shared__ __align__(16) __bf16 Bs[2][128*64];    // 32 KB
    int t = threadIdx.x;
    int w = t >> 6, lane = t & 63;
    int ln = lane & 15, quad = lane >> 4;
    int m0 = blockIdx.x * 64, n0 = blockIdx.y * 128;
    int wm = (w >> 1) * 32, wn = (w & 1) * 64;

    f32x4 acc[2][4] = {};

    const char* Ab = (const char*)A + (size_t)m0 * K * 2;
    const char* Bb = (const char*)Bt + (size_t)n0 * K * 2;
    int fb = w*64 + lane;
    size_t gaA[2]; int loA[2];
    #pragma unroll
    for (int ra = 0; ra < 2; ++ra) {
        int f = fb + 256*ra;
        gaA[ra] = (size_t)(f >> 3) * (K*2) + (size_t)(((f & 7) ^ ((f >> 3) & 7)) * 16);
        loA[ra] = (w*64 + 256*ra) * 16;      // wave-uniform LDS base
    }
    size_t gaB[4]; int loB[4];
    #pragma unroll
    for (int rb = 0; rb < 4; ++rb) {
        int f = fb + 256*rb;
        gaB[rb] = (size_t)(f >> 3) * (K*2) + (size_t)(((f & 7) ^ ((f >> 3) & 7)) * 16);
        loB[rb] = (w*64 + 256*rb) * 16;      // wave-uniform LDS base
    }

    int nIt = K >> 6;

    #define STAGE64B(buf, itv) do {                                        \
        size_t kb_ = (size_t)(itv) * 128;                                  \
        _Pragma("unroll")                                                  \
        for (int ra = 0; ra < 2; ++ra)                                     \
            glds16(Ab + gaA[ra] + kb_, (char*)As[buf] + loA[ra]);          \
        _Pragma("unroll")                                                  \
        for (int rb = 0; rb < 4; ++rb)                                     \
            glds16(Bb + gaB[rb] + kb_, (char*)Bs[buf] + loB[rb]);          \
    } while (0)

    STAGE64B(0, 0);

    for (int it = 0; it < nIt; ++it) {
        int p = it & 1;
        __syncthreads();               // staging of buf p complete; reads of p^1 retired
        if (it + 1 < nIt)
            STAGE64B(p^1, it + 1);
        bf16x8 af[2][2], bfr[4][2];
        #pragma unroll
        for (int i = 0; i < 2; ++i) {
            int row = wm + i*16 + ln;
            #pragma unroll
            for (int kk = 0; kk < 2; ++kk)
                af[i][kk] = __builtin_bit_cast(bf16x8,
                    *(const uint4*)&As[p][row*64 + (((kk*4 + quad) ^ (row & 7)) * 8)]);
        }
        #pragma unroll
        for (int j = 0; j < 4; ++j) {
            int row = wn + j*16 + ln;
            #pragma unroll
            for (int kk = 0; kk < 2; ++kk)
                bfr[j][kk] = __builtin_bit_cast(bf16x8,
                    *(const uint4*)&Bs[p][row*64 + (((kk*4 + quad) ^ (row & 7)) * 8)]);
        }
        #pragma unroll
        for (int kk = 0; kk < 2; ++kk)
            #pragma unroll
            for (int i = 0; i < 2; ++i)
                #pragma unroll
                for (int j = 0; j < 4; ++j)
                    acc[i][j] = __builtin_amdgcn_mfma_f32_16x16x32_bf16(
                                    af[i][kk], bfr[j][kk], acc[i][j], 0, 0, 0);
    }
    #undef STAGE64B

    #pragma unroll
    for (int i = 0; i < 2; ++i) {
        #pragma unroll
        for (int r = 0; r < 4; ++r) {
            int row = m0 + wm + i*16 + quad*4 + r;
            #pragma unroll
            for (int j = 0; j < 4; ++j) {
                int col = n0 + wn + j*16 + ln;
                if (col < ncols) {
                    float v = acc[i][j][r];
                    if (bias) v += bias[col];
                    if (relu) v = fmaxf(v, 0.f);
                    if (res)  v += res[(size_t)row*ldc + col];
                    if (outF) outF[(size_t)row*ldc + col] = v;
                    if (outB) outB[(size_t)row*ldc + col] = (__bf16)v;
                }
            }
        }
    }
}

// ---------------------------------------------------------------- TM=128 BK=64 SINGLE-BUF GEMM (QKV/FFN1)
// R12 model: staged-rate ~ 2.5 TB/s x resident blocks (sat ~8.8). 2-buf TM128/BK64 = 64 KB
// -> 2 blk -> 4.4 TB/s (measured 66 us). SINGLE buffer = 32 KB -> LDS allows 5 blk;
// __launch_bounds__(256,3) keeps VGPR <= 170 so >= 3 blk resident. Amplification
// (1/128+1/128) = 0.0156, -33% staged bytes vs TM=64. Intra-block overlap lost; cross-block
// wave-level overlap (m114) sustains the rate — that's what drives the 2-buf kernels anyway.
// Only for N>=1152 GEMMs (grid >= 4.5 blk/CU). Loop: { STAGE; sync; compute; sync }.
__global__ __launch_bounds__(256, 3)
void gemm128s(const __bf16* __restrict__ A, const __bf16* __restrict__ Bt,
              const float* __restrict__ bias,
              float* outF, __bf16* outB,
              int K, int ldc, int ncols, int relu)
{
    __shared__ __align__(16) __bf16 As[128*64];    // 16 KB
    __shared__ __align__(16) __bf16 Bs[128*64];    // 16 KB
    int t = threadIdx.x;
    int w = t >> 6, lane = t & 63;
    int ln = lane & 15, quad = lane >> 4;
    int m0 = blockIdx.x * 128, n0 = blockIdx.y * 128;
    int wm = (w >> 1) * 64, wn = (w & 1) * 64;

    f32x4 acc[4][4] = {};

    const char* Ab = (const char*)A + (size_t)m0 * K * 2;
    const char* Bb = (const char*)Bt + (size_t)n0 * K * 2;
    int fb = w*64 + lane;
    size_t gaA[4]; int loA[4];
    #pragma unroll
    for (int ra = 0; ra < 4; ++ra) {
        int f = fb + 256*ra;            // f in [0,1024): rows 0..127, chunks 0..7
        gaA[ra] = (size_t)(f >> 3) * (K*2) + (size_t)(((f & 7) ^ ((f >> 3) & 7)) * 16);
        loA[ra] = (w*64 + 256*ra) * 16; // wave-uniform LDS base
    }
    size_t gaB[4]; int loB[4];
    #pragma unroll
    for (int rb = 0; rb < 4; ++rb) {
        int f = fb + 256*rb;
        gaB[rb] = (size_t)(f >> 3) * (K*2) + (size_t)(((f & 7) ^ ((f >> 3) & 7)) * 16);
        loB[rb] = (w*64 + 256*rb) * 16;
    }

    int nIt = K >> 6;   // K=384 -> 6

    for (int it = 0; it < nIt; ++it) {
        size_t kb = (size_t)it * 128;
        #pragma unroll
        for (int ra = 0; ra < 4; ++ra)
            glds16(Ab + gaA[ra] + kb, (char*)As + loA[ra]);
        #pragma unroll
        for (int rb = 0; rb < 4; ++rb)
            glds16(Bb + gaB[rb] + kb, (char*)Bs + loB[rb]);
        __syncthreads();               // drains vmcnt: staging visible to all waves
        bf16x8 af[4][2], bfr[4][2];
        #pragma unroll
        for (int i = 0; i < 4; ++i) {
            int row = wm + i*16 + ln;
            #pragma unroll
            for (int kk = 0; kk < 2; ++kk)
                af[i][kk] = __builtin_bit_cast(bf16x8,
                    *(const uint4*)&As[row*64 + (((kk*4 + quad) ^ (row & 7)) * 8)]);
        }
        #pragma unroll
        for (int j = 0; j < 4; ++j) {
            int row = wn + j*16 + ln;
            #pragma unroll
            for (int kk = 0; kk < 2; ++kk)
                bfr[j][kk] = __builtin_bit_cast(bf16x8,
                    *(const uint4*)&Bs[row*64 + (((kk*4 + quad) ^ (row & 7)) * 8)]);
        }
        #pragma unroll
        for (int kk = 0; kk < 2; ++kk)
            #pragma unroll
            for (int i = 0; i < 4; ++i)
                #pragma unroll
                for (int j = 0; j < 4; ++j)
                    acc[i][j] = __builtin_amdgcn_mfma_f32_16x16x32_bf16(
                                    af[i][kk], bfr[j][kk], acc[i][j], 0, 0, 0);
        __syncthreads();               // all waves' ds_reads retired before next overwrite
    }

    #pragma unroll
    for (int i = 0; i < 4; ++i) {
        #pragma unroll
        for (int r = 0; r < 4; ++r) {
            int row = m0 + wm + i*16 + quad*4 + r;
            #pragma unroll
            for (int j = 0; j < 4; ++j) {
                int col = n0 + wn + j*16 + ln;
                if (col < ncols) {
                    float v = acc[i][j][r];
                    if (bias) v += bias[col];
                    if (relu) v = fmaxf(v, 0.f);
                    if (outF) outF[(size_t)row*ldc + col] = v;
                    if (outB) outB[(size_t)row*ldc + col] = (__bf16)v;
                }
            }
        }
    }
}

// ---------------------------------------------------------------- MFMA flash attention
__global__ __launch_bounds__(256, 2)
void attn4(const __bf16* __restrict__ qkv, __bf16* __restrict__ o)
{
    __shared__ __align__(16) __bf16 Ks[256*72];
    __shared__ __align__(16) __bf16 Vt[64*264];
    __shared__ __align__(16) __bf16 Pw[4][32*40];
    int bid = blockIdx.x;
    int h = bid % H_;
    int b = bid / H_;
    int t = threadIdx.x;
    int w = t >> 6, lane = t & 63;
    int ln = lane & 15, quad = lane >> 4;
    const size_t rowb = (size_t)b * T_ * QKVN;
    const int hoff = h * HS_;
    const float scale = 0.05103103630798288f;   // 1/sqrt(384)

    for (int c = t; c < 2048; c += 256) {
        int r = c >> 3, e0 = (c & 7) * 8;
        uint4 uk = *(const uint4*)(qkv + rowb + (size_t)r*QKVN + 384 + hoff + e0);
        *(uint4*)&Ks[r*72 + e0] = uk;
        uint4 uv = *(const uint4*)(qkv + rowb + (size_t)r*QKVN + 768 + hoff + e0);
        bf16x8 v8 = u4_to_bf8(uv);
        #pragma unroll
        for (int j = 0; j < 8; ++j) {
            int e = e0 + j;
            Vt[e*264 + (((r >> 3) ^ ((e >> 3) & 3)) * 8) + (r & 7)] = v8[j];
        }
    }

    int qis[2] = { w, 7 - w };
    uint4 Qf[2][2][2];
    #pragma unroll
    for (int tl = 0; tl < 2; ++tl)
        #pragma unroll
        for (int mi = 0; mi < 2; ++mi)
            #pragma unroll
            for (int kc = 0; kc < 2; ++kc)
                Qf[tl][mi][kc] = *(const uint4*)(qkv + rowb +
                    (size_t)(qis[tl]*32 + mi*16 + ln)*QKVN + hoff + kc*32 + quad*8);

    __syncthreads();

    __bf16* P = Pw[w];
    #pragma unroll
    for (int tl = 0; tl < 2; ++tl) {
        int qi = qis[tl];
        f32x4 O[2][4] = {};
        float mst[2][4], lst[2][4];
        #pragma unroll
        for (int mi = 0; mi < 2; ++mi)
            #pragma unroll
            for (int r = 0; r < 4; ++r) { mst[mi][r] = -INFINITY; lst[mi][r] = 0.f; }

        for (int st = 0; st <= qi; ++st) {
            int sb = st * 32;
            f32x4 S[2][2] = {};
            #pragma unroll
            for (int kc = 0; kc < 2; ++kc) {
                uint4 Kf[2];
                #pragma unroll
                for (int ji = 0; ji < 2; ++ji)
                    Kf[ji] = *(const uint4*)&Ks[(sb + ji*16 + ln)*72 + kc*32 + quad*8];
                __builtin_amdgcn_s_setprio(1);
                #pragma unroll
                for (int mi = 0; mi < 2; ++mi) {
                    bf16x8 qa = __builtin_bit_cast(bf16x8, Qf[tl][mi][kc]);
                    #pragma unroll
                    for (int ji = 0; ji < 2; ++ji)
                        S[mi][ji] = __builtin_amdgcn_mfma_f32_16x16x32_bf16(
                            qa, __builtin_bit_cast(bf16x8, Kf[ji]), S[mi][ji], 0, 0, 0);
                }
                __builtin_amdgcn_s_setprio(0);
            }
            int diag = (st == qi);
            #pragma unroll
            for (int mi = 0; mi < 2; ++mi)
                #pragma unroll
                for (int ji = 0; ji < 2; ++ji)
                    #pragma unroll
                    for (int r = 0; r < 4; ++r) {
                        float v = S[mi][ji][r] * scale;
                        if (diag && (ji*16 + ln) > (mi*16 + quad*4 + r)) v = -INFINITY;
                        S[mi][ji][r] = v;
                    }
            #pragma unroll
            for (int mi = 0; mi < 2; ++mi)
                #pragma unroll
                for (int r = 0; r < 4; ++r) {
                    float mx = fmaxf(S[mi][0][r], S[mi][1][r]);
                    #pragma unroll
                    for (int off = 1; off < 16; off <<= 1)
                        mx = fmaxf(mx, __shfl_xor(mx, off));
                    float mn = fmaxf(mst[mi][r], mx);
                    float al = __expf(mst[mi][r] - mn);
                    mst[mi][r] = mn;
                    float p0 = __expf(S[mi][0][r] - mn);
                    float p1 = __expf(S[mi][1][r] - mn);
                    S[mi][0][r] = p0; S[mi][1][r] = p1;
                    float rs = p0 + p1;
                    #pragma unroll
                    for (int off = 1; off < 16; off <<= 1)
                        rs += __shfl_xor(rs, off);
                    lst[mi][r] = lst[mi][r]*al + rs;
                    #pragma unroll
                    for (int ei = 0; ei < 4; ++ei) O[mi][ei][r] *= al;
                }
            #pragma unroll
            for (int mi = 0; mi < 2; ++mi)
                #pragma unroll
                for (int ji = 0; ji < 2; ++ji)
                    #pragma unroll
                    for (int r = 0; r < 4; ++r)
                        P[(mi*16 + quad*4 + r)*40 + ji*16 + ln] = (__bf16)S[mi][ji][r];
            uint4 Pf[2], Vf[4];
            #pragma unroll
            for (int mi = 0; mi < 2; ++mi)
                Pf[mi] = *(const uint4*)&P[(mi*16 + ln)*40 + quad*8];
            #pragma unroll
            for (int ei = 0; ei < 4; ++ei) {
                int e = ei*16 + ln;
                Vf[ei] = *(const uint4*)&Vt[e*264 + (((st*4 + quad) ^ ((e >> 3) & 3)) * 8)];
            }
            __builtin_amdgcn_s_setprio(1);
            #pragma unroll
            for (int mi = 0; mi < 2; ++mi)
                #pragma unroll
                for (int ei = 0; ei < 4; ++ei)
                    O[mi][ei] = __builtin_amdgcn_mfma_f32_16x16x32_bf16(
                        __builtin_bit_cast(bf16x8, Pf[mi]),
                        __builtin_bit_cast(bf16x8, Vf[ei]), O[mi][ei], 0, 0, 0);
            __builtin_amdgcn_s_setprio(0);
        }
        #pragma unroll
        for (int mi = 0; mi < 2; ++mi)
            #pragma unroll
            for (int r = 0; r < 4; ++r) {
                float inv = 1.0f / lst[mi][r];
                size_t row = (size_t)(b*T_ + qi*32 + mi*16 + quad*4 + r);
                #pragma unroll
                for (int ei = 0; ei < 4; ++ei)
                    o[row*D_ + hoff + ei*16 + ln] = (__bf16)(O[mi][ei][r] * inv);
            }
    }
}

// ---------------------------------------------------------------- loss
__global__ __launch_bounds__(256)
void loss2(const float* __restrict__ logits,
           const int* __restrict__ tg,
           float* __restrict__ loss)
{
    int t = threadIdx.x;
    int g16 = t >> 4, ln = t & 15;
    int row = blockIdx.x * 16 + g16;
    const float* lr = logits + (size_t)row * V_;
    float v0 = lr[ln], v1 = lr[16+ln], v2 = lr[32+ln], v3 = lr[48+ln];
    float v4 = (ln == 0) ? lr[64] : -INFINITY;
    float m = fmaxf(fmaxf(fmaxf(v0, v1), fmaxf(v2, v3)), v4);
    #pragma unroll
    for (int off = 1; off < 16; off <<= 1) m = fmaxf(m, __shfl_xor(m, off));
    float s = __expf(v0-m) + __expf(v1-m) + __expf(v2-m) + __expf(v3-m);
    if (ln == 0) s += __expf(v4-m);
    #pragma unroll
    for (int off = 1; off < 16; off <<= 1) s += __shfl_xor(s, off);
    float val = 0.f;
    if (ln == 0)
        val = -(lr[tg[row]] - m - __logf(s)) * (1.0f/ROWS);
    #pragma unroll
    for (int off = 16; off < 64; off <<= 1) val += __shfl_xor(val, off);
    __shared__ float red[4];
    int w = t >> 6;
    if ((t & 63) == 0) red[w] = val;
    __syncthreads();
    if (t == 0)
        atomicAdd(loss, red[0]+red[1]+red[2]+red[3]);
}

// ---------------------------------------------------------------- launch
extern "C" void kernel_launch(void* const* d_in, const int* in_sizes, int n_in,
                              void* d_out, int out_size, void* d_ws, size_t ws_size,
                              hipStream_t stream)
{
    const int*   idx     = (const int*)  d_in[0];
    const int*   targets = (const int*)  d_in[1];
    const float* tok     = (const float*)d_in[2];
    const float* pos     = (const float*)d_in[3];
    const float* Wq      = (const float*)d_in[4];
    const float* Wk      = (const float*)d_in[5];
    const float* Wv      = (const float*)d_in[6];
    const float* Wproj   = (const float*)d_in[7];
    const float* bproj   = (const float*)d_in[8];
    const float* W1      = (const float*)d_in[9];
    const float* b1      = (const float*)d_in[10];
    const float* W2      = (const float*)d_in[11];
    const float* b2      = (const float*)d_in[12];
    const float* ln1g    = (const float*)d_in[13];
    const float* ln1b    = (const float*)d_in[14];
    const float* lnfg    = (const float*)d_in[15];
    const float* lnfb    = (const float*)d_in[16];
    const float* Whead   = (const float*)d_in[17];
    const float* bhead   = (const float*)d_in[18];

    float* logits = (float*)d_out;
    float* loss   = logits + (size_t)ROWS * V_;

    const size_t SZ = (size_t)ROWS * D_;             // 6291456
    const size_t RGELEMS = (size_t)ROWS * 4 * D_;    // 25165824 bf16 elems

    float*  x   = (float*)d_ws;                      // SZ f32
    __bf16* yb  = (__bf16*)(x + SZ);                 // SZ bf16
    __bf16* Rg  = yb + SZ;                           // RGELEMS bf16 (qkv / hid)
    __bf16* qkv = Rg;                                // ROWS*1152
    __bf16* hid = Rg;                                // ROWS*1536
    __bf16* o   = Rg + RGELEMS;                      // SZ bf16
    __bf16* qkvT  = o + SZ;                          // L*1152*384
    __bf16* projT = qkvT + (size_t)L_*QKVN*D_;       // L*384*384
    __bf16* w1T   = projT + (size_t)L_*D_*D_;        // L*1536*384
    __bf16* w2T   = w1T + (size_t)L_*D_*4*D_;        // L*384*1536
    __bf16* headT = w2T + (size_t)L_*D_*4*D_;        // 128*384

    // weight conversion (transpose to [N][K] bf16)
    transpose_cast<<<dim3(2,12,36),256,0,stream>>>(Wq, qkvT, D_, HS_, H_,
        (long)QKVN*D_, (long)HS_*D_, 0L);
    transpose_cast<<<dim3(2,12,36),256,0,stream>>>(Wk, qkvT, D_, HS_, H_,
        (long)QKVN*D_, (long)HS_*D_, (long)D_*D_);
    transpose_cast<<<dim3(2,12,36),256,0,stream>>>(Wv, qkvT, D_, HS_, H_,
        (long)QKVN*D_, (long)HS_*D_, 2L*D_*D_);
    transpose_cast<<<dim3(12,12,6),256,0,stream>>>(Wproj, projT, D_, D_, 1,
        (long)D_*D_, 0L, 0L);
    transpose_cast<<<dim3(48,12,6),256,0,stream>>>(W1, w1T, D_, 4*D_, 1,
        (long)D_*4*D_, 0L, 0L);
    transpose_cast<<<dim3(12,48,6),256,0,stream>>>(W2, w2T, 4*D_, D_, 1,
        (long)D_*4*D_, 0L, 0L);
    head_prep<<<(128*D_)/256, 256, 0, stream>>>(Whead, headT);

    embed_kernel<<<(ROWS*D_/4)/256, 256, 0, stream>>>(idx, tok, pos, x);

    for (int l = 0; l < L_; ++l) {
        ln4<<<ROWS/4, 256, 0, stream>>>(x, ln1g + l*D_, ln1b + l*D_, yb);
        gemm128s<<<dim3(ROWS/128, QKVN/128), 256, 0, stream>>>(
            yb, qkvT + (size_t)l*QKVN*D_, nullptr, nullptr, qkv,
            D_, QKVN, QKVN, 0);
        attn4<<<B_*H_, 256, 0, stream>>>(qkv, o);
        gemm64b<<<dim3(ROWS/64, D_/128), 256, 0, stream>>>(
            o, projT + (size_t)l*D_*D_, bproj + l*D_, x, x, nullptr,
            D_, D_, D_, 0);
        ln4<<<ROWS/4, 256, 0, stream>>>(x, ln1g + l*D_, ln1b + l*D_, yb);
        gemm128s<<<dim3(ROWS/128, 4*D_/128), 256, 0, stream>>>(
            yb, w1T + (size_t)l*D_*4*D_, b1 + l*4*D_, nullptr, hid,
            D_, 4*D_, 4*D_, 1);
        gemm64b<<<dim3(ROWS/64, D_/128), 256, 0, stream>>>(
            hid, w2T + (size_t)l*D_*4*D_, b2 + l*D_, x, x, nullptr,
            4*D_, D_, D_, 0);
    }
    ln4<<<ROWS/4, 256, 0, stream>>>(x, lnfg, lnfb, yb);
    gemm64b<<<dim3(ROWS/64, 1), 256, 0, stream>>>(
        yb, headT, bhead, nullptr, logits, nullptr,
        D_, V_, V_, 0);
    hipMemsetAsync(loss, 0, sizeof(float), stream);
    loss2<<<ROWS/16, 256, 0, stream>>>(logits, targets, loss);
}

// Round 14
// 1292.814 us; speedup vs baseline: 1.1186x; 1.0230x over previous
//
#include <hip/hip_runtime.h>
#include <math.h>

#define L_ 6
#define H_ 6
#define HS_ 64
#define D_ 384
#define T_ 256
#define V_ 65
#define B_ 64
#define ROWS (B_*T_)        // 16384
#define QKVN 1152
#define EPS_ 1e-5f

typedef __attribute__((ext_vector_type(8))) __bf16 bf16x8;
typedef __attribute__((ext_vector_type(2))) __bf16 bf16x2;
typedef __attribute__((ext_vector_type(4))) float f32x4;

__device__ __forceinline__ bf16x8 u4_to_bf8(uint4 u) {
    return __builtin_bit_cast(bf16x8, u);
}

// async global->LDS, 16B per lane. lds ptr wave-uniform; HW scatters lane i to lds + i*16.
__device__ __forceinline__ void glds16(const void* g, void* l) {
    __builtin_amdgcn_global_load_lds(
        (const __attribute__((address_space(1))) void*)g,
        (__attribute__((address_space(3))) void*)l, 16, 0, 0);
}

// ---------------------------------------------------------------- embedding
__global__ __launch_bounds__(256)
void embed_kernel(const int* __restrict__ idx,
                  const float* __restrict__ tok,
                  const float* __restrict__ pos,
                  float* __restrict__ x) {
    int i = blockIdx.x * blockDim.x + threadIdx.x;   // < ROWS*D_/4
    int e = i * 4;
    int d = e % D_;
    int row = e / D_;
    int t = row % T_;
    const float4 tv = *(const float4*)(tok + (size_t)idx[row]*D_ + d);
    const float4 pv = *(const float4*)(pos + (size_t)t*D_ + d);
    float4 r;
    r.x = tv.x + pv.x; r.y = tv.y + pv.y;
    r.z = tv.z + pv.z; r.w = tv.w + pv.w;
    *(float4*)(x + e) = r;
}

// ---------------------------------------------------------------- layernorm
__global__ __launch_bounds__(256)
void ln4(const float* __restrict__ x,
         const float* __restrict__ g,
         const float* __restrict__ b,
         __bf16* __restrict__ yb) {
    int w = threadIdx.x >> 6, lane = threadIdx.x & 63;
    int row = blockIdx.x * 4 + w;
    const float* xr = x + (size_t)row * D_;
    float2 v[3];
    #pragma unroll
    for (int i = 0; i < 3; ++i) v[i] = *(const float2*)(xr + lane*2 + 128*i);
    float s = 0.f, sq = 0.f;
    #pragma unroll
    for (int i = 0; i < 3; ++i) {
        s += v[i].x + v[i].y;
        sq += v[i].x*v[i].x + v[i].y*v[i].y;
    }
    for (int off = 32; off; off >>= 1) {
        s  += __shfl_xor(s,  off);
        sq += __shfl_xor(sq, off);
    }
    float mean = s * (1.0f/D_);
    float var  = sq * (1.0f/D_) - mean*mean;
    float rstd = rsqrtf(var + EPS_);
    __bf16* yr = yb + (size_t)row * D_;
    #pragma unroll
    for (int i = 0; i < 3; ++i) {
        int c = lane*2 + 128*i;
        float2 gv = *(const float2*)(g + c);
        float2 bv = *(const float2*)(b + c);
        bf16x2 pr;
        pr[0] = (__bf16)((v[i].x-mean)*rstd*gv.x + bv.x);
        pr[1] = (__bf16)((v[i].y-mean)*rstd*gv.y + bv.y);
        *(bf16x2*)(yr + c) = pr;
    }
}

// ---------------------------------------------------------------- transpose+cast
__global__ __launch_bounds__(256)
void transpose_cast(const float* __restrict__ src, __bf16* __restrict__ dst,
                    int R, int C, int zdiv, long sA, long sB, long dbase)
{
    __shared__ float tile[32][33];
    int z = blockIdx.z;
    const float* s = src + (long)z * R * C;
    __bf16* d = dst + dbase + (long)(z / zdiv) * sA + (long)(z % zdiv) * sB;
    int c0 = blockIdx.x * 32, r0 = blockIdx.y * 32;
    int t = threadIdx.x;
    int tr = t >> 3, tc = (t & 7) * 4;
    float4 v = *(const float4*)(s + (long)(r0 + tr) * C + c0 + tc);
    tile[tr][tc+0] = v.x; tile[tr][tc+1] = v.y;
    tile[tr][tc+2] = v.z; tile[tr][tc+3] = v.w;
    __syncthreads();
    #pragma unroll
    for (int j = 0; j < 4; ++j)
        d[(long)(c0 + tr) * R + r0 + tc + j] = (__bf16)tile[tc+j][tr];
}

// head weight: Whead [384][65] fp32 -> headT [128][384] bf16 (zero-padded rows 65..127)
__global__ __launch_bounds__(256)
void head_prep(const float* __restrict__ Whead, __bf16* __restrict__ headT) {
    int i = blockIdx.x * 256 + threadIdx.x;   // < 128*384
    int n = i / D_, k = i % D_;
    headT[i] = (n < V_) ? (__bf16)Whead[k*V_ + n] : (__bf16)0.0f;
}

// ---------------------------------------------------------------- TM=64 BK=64 SINGLE-BUF GEMM (proj/FFN2/head)
// R13 model: staged-rate scales with resident blocks (2-buf 48 KB -> 3 blk -> 7.6-9.4 TB/s).
// Single buffer: 24 KB -> 5-6 resident blocks (LDS 6, VGPR ~100 -> 5). Same tiles, same
// swizzle, same staging addressing as the proven gemm64b; loop is the R13-proven
// single-buf structure { STAGE; sync; compute; sync } (refcheck'd in gemm128s).
__global__ __launch_bounds__(256, 4)
void gemm64s(const __bf16* __restrict__ A, const __bf16* __restrict__ Bt,
             const float* __restrict__ bias, const float* res,
             float* outF, __bf16* outB,
             int K, int ldc, int ncols, int relu)
{
    __shared__ __align__(16) __bf16 As[64*64];     // 8 KB
    __shared__ __align__(16) __bf16 Bs[128*64];    // 16 KB
    int t = threadIdx.x;
    int w = t >> 6, lane = t & 63;
    int ln = lane & 15, quad = lane >> 4;
    int m0 = blockIdx.x * 64, n0 = blockIdx.y * 128;
    int wm = (w >> 1) * 32, wn = (w & 1) * 64;

    f32x4 acc[2][4] = {};

    const char* Ab = (const char*)A + (size_t)m0 * K * 2;
    const char* Bb = (const char*)Bt + (size_t)n0 * K * 2;
    int fb = w*64 + lane;
    // flat id f covers row f>>3, 16B-chunk f&7; source chunk pre-swizzled by row&7.
    size_t gaA[2]; int loA[2];
    #pragma unroll
    for (int ra = 0; ra < 2; ++ra) {
        int f = fb + 256*ra;
        gaA[ra] = (size_t)(f >> 3) * (K*2) + (size_t)(((f & 7) ^ ((f >> 3) & 7)) * 16);
        loA[ra] = (w*64 + 256*ra) * 16;      // wave-uniform LDS base
    }
    size_t gaB[4]; int loB[4];
    #pragma unroll
    for (int rb = 0; rb < 4; ++rb) {
        int f = fb + 256*rb;
        gaB[rb] = (size_t)(f >> 3) * (K*2) + (size_t)(((f & 7) ^ ((f >> 3) & 7)) * 16);
        loB[rb] = (w*64 + 256*rb) * 16;      // wave-uniform LDS base
    }

    int nIt = K >> 6;   // K=384 -> 6, K=1536 -> 24

    for (int it = 0; it < nIt; ++it) {
        size_t kb = (size_t)it * 128;
        #pragma unroll
        for (int ra = 0; ra < 2; ++ra)
            glds16(Ab + gaA[ra] + kb, (char*)As + loA[ra]);
        #pragma unroll
        for (int rb = 0; rb < 4; ++rb)
            glds16(Bb + gaB[rb] + kb, (char*)Bs + loB[rb]);
        __syncthreads();               // drains vmcnt: staging visible to all waves
        bf16x8 af[2][2], bfr[4][2];
        #pragma unroll
        for (int i = 0; i < 2; ++i) {
            int row = wm + i*16 + ln;
            #pragma unroll
            for (int kk = 0; kk < 2; ++kk)
                af[i][kk] = __builtin_bit_cast(bf16x8,
                    *(const uint4*)&As[row*64 + (((kk*4 + quad) ^ (row & 7)) * 8)]);
        }
        #pragma unroll
        for (int j = 0; j < 4; ++j) {
            int row = wn + j*16 + ln;
            #pragma unroll
            for (int kk = 0; kk < 2; ++kk)
                bfr[j][kk] = __builtin_bit_cast(bf16x8,
                    *(const uint4*)&Bs[row*64 + (((kk*4 + quad) ^ (row & 7)) * 8)]);
        }
        #pragma unroll
        for (int kk = 0; kk < 2; ++kk)
            #pragma unroll
            for (int i = 0; i < 2; ++i)
                #pragma unroll
                for (int j = 0; j < 4; ++j)
                    acc[i][j] = __builtin_amdgcn_mfma_f32_16x16x32_bf16(
                                    af[i][kk], bfr[j][kk], acc[i][j], 0, 0, 0);
        __syncthreads();               // all waves' ds_reads retired before next overwrite
    }

    #pragma unroll
    for (int i = 0; i < 2; ++i) {
        #pragma unroll
        for (int r = 0; r < 4; ++r) {
            int row = m0 + wm + i*16 + quad*4 + r;
            #pragma unroll
            for (int j = 0; j < 4; ++j) {
                int col = n0 + wn + j*16 + ln;
                if (col < ncols) {
                    float v = acc[i][j][r];
                    if (bias) v += bias[col];
                    if (relu) v = fmaxf(v, 0.f);
                    if (res)  v += res[(size_t)row*ldc + col];
                    if (outF) outF[(size_t)row*ldc + col] = v;
                    if (outB) outB[(size_t)row*ldc + col] = (__bf16)v;
                }
            }
        }
    }
}

// ---------------------------------------------------------------- TM=128 BK=64 SINGLE-BUF GEMM (QKV/FFN1)
// R13-proven (refcheck'd, moved QKV/FFN1 off the hot list). 32 KB LDS -> high residency,
// amplification (1/128+1/128)=0.0156. Only for N>=1152 GEMMs (grid >= 4.5 blk/CU).
__global__ __launch_bounds__(256, 3)
void gemm128s(const __bf16* __restrict__ A, const __bf16* __restrict__ Bt,
              const float* __restrict__ bias,
              float* outF, __bf16* outB,
              int K, int ldc, int ncols, int relu)
{
    __shared__ __align__(16) __bf16 As[128*64];    // 16 KB
    __shared__ __align__(16) __bf16 Bs[128*64];    // 16 KB
    int t = threadIdx.x;
    int w = t >> 6, lane = t & 63;
    int ln = lane & 15, quad = lane >> 4;
    int m0 = blockIdx.x * 128, n0 = blockIdx.y * 128;
    int wm = (w >> 1) * 64, wn = (w & 1) * 64;

    f32x4 acc[4][4] = {};

    const char* Ab = (const char*)A + (size_t)m0 * K * 2;
    const char* Bb = (const char*)Bt + (size_t)n0 * K * 2;
    int fb = w*64 + lane;
    size_t gaA[4]; int loA[4];
    #pragma unroll
    for (int ra = 0; ra < 4; ++ra) {
        int f = fb + 256*ra;            // f in [0,1024): rows 0..127, chunks 0..7
        gaA[ra] = (size_t)(f >> 3) * (K*2) + (size_t)(((f & 7) ^ ((f >> 3) & 7)) * 16);
        loA[ra] = (w*64 + 256*ra) * 16; // wave-uniform LDS base
    }
    size_t gaB[4]; int loB[4];
    #pragma unroll
    for (int rb = 0; rb < 4; ++rb) {
        int f = fb + 256*rb;
        gaB[rb] = (size_t)(f >> 3) * (K*2) + (size_t)(((f & 7) ^ ((f >> 3) & 7)) * 16);
        loB[rb] = (w*64 + 256*rb) * 16;
    }

    int nIt = K >> 6;   // K=384 -> 6

    for (int it = 0; it < nIt; ++it) {
        size_t kb = (size_t)it * 128;
        #pragma unroll
        for (int ra = 0; ra < 4; ++ra)
            glds16(Ab + gaA[ra] + kb, (char*)As + loA[ra]);
        #pragma unroll
        for (int rb = 0; rb < 4; ++rb)
            glds16(Bb + gaB[rb] + kb, (char*)Bs + loB[rb]);
        __syncthreads();               // drains vmcnt: staging visible to all waves
        bf16x8 af[4][2], bfr[4][2];
        #pragma unroll
        for (int i = 0; i < 4; ++i) {
            int row = wm + i*16 + ln;
            #pragma unroll
            for (int kk = 0; kk < 2; ++kk)
                af[i][kk] = __builtin_bit_cast(bf16x8,
                    *(const uint4*)&As[row*64 + (((kk*4 + quad) ^ (row & 7)) * 8)]);
        }
        #pragma unroll
        for (int j = 0; j < 4; ++j) {
            int row = wn + j*16 + ln;
            #pragma unroll
            for (int kk = 0; kk < 2; ++kk)
                bfr[j][kk] = __builtin_bit_cast(bf16x8,
                    *(const uint4*)&Bs[row*64 + (((kk*4 + quad) ^ (row & 7)) * 8)]);
        }
        #pragma unroll
        for (int kk = 0; kk < 2; ++kk)
            #pragma unroll
            for (int i = 0; i < 4; ++i)
                #pragma unroll
                for (int j = 0; j < 4; ++j)
                    acc[i][j] = __builtin_amdgcn_mfma_f32_16x16x32_bf16(
                                    af[i][kk], bfr[j][kk], acc[i][j], 0, 0, 0);
        __syncthreads();               // all waves' ds_reads retired before next overwrite
    }

    #pragma unroll
    for (int i = 0; i < 4; ++i) {
        #pragma unroll
        for (int r = 0; r < 4; ++r) {
            int row = m0 + wm + i*16 + quad*4 + r;
            #pragma unroll
            for (int j = 0; j < 4; ++j) {
                int col = n0 + wn + j*16 + ln;
                if (col < ncols) {
                    float v = acc[i][j][r];
                    if (bias) v += bias[col];
                    if (relu) v = fmaxf(v, 0.f);
                    if (outF) outF[(size_t)row*ldc + col] = v;
                    if (outB) outB[(size_t)row*ldc + col] = (__bf16)v;
                }
            }
        }
    }
}

// ---------------------------------------------------------------- MFMA flash attention
__global__ __launch_bounds__(256, 2)
void attn4(const __bf16* __restrict__ qkv, __bf16* __restrict__ o)
{
    __shared__ __align__(16) __bf16 Ks[256*72];
    __shared__ __align__(16) __bf16 Vt[64*264];
    __shared__ __align__(16) __bf16 Pw[4][32*40];
    int bid = blockIdx.x;
    int h = bid % H_;
    int b = bid / H_;
    int t = threadIdx.x;
    int w = t >> 6, lane = t & 63;
    int ln = lane & 15, quad = lane >> 4;
    const size_t rowb = (size_t)b * T_ * QKVN;
    const int hoff = h * HS_;
    const float scale = 0.05103103630798288f;   // 1/sqrt(384)

    for (int c = t; c < 2048; c += 256) {
        int r = c >> 3, e0 = (c & 7) * 8;
        uint4 uk = *(const uint4*)(qkv + rowb + (size_t)r*QKVN + 384 + hoff + e0);
        *(uint4*)&Ks[r*72 + e0] = uk;
        uint4 uv = *(const uint4*)(qkv + rowb + (size_t)r*QKVN + 768 + hoff + e0);
        bf16x8 v8 = u4_to_bf8(uv);
        #pragma unroll
        for (int j = 0; j < 8; ++j) {
            int e = e0 + j;
            Vt[e*264 + (((r >> 3) ^ ((e >> 3) & 3)) * 8) + (r & 7)] = v8[j];
        }
    }

    int qis[2] = { w, 7 - w };
    uint4 Qf[2][2][2];
    #pragma unroll
    for (int tl = 0; tl < 2; ++tl)
        #pragma unroll
        for (int mi = 0; mi < 2; ++mi)
            #pragma unroll
            for (int kc = 0; kc < 2; ++kc)
                Qf[tl][mi][kc] = *(const uint4*)(qkv + rowb +
                    (size_t)(qis[tl]*32 + mi*16 + ln)*QKVN + hoff + kc*32 + quad*8);

    __syncthreads();

    __bf16* P = Pw[w];
    #pragma unroll
    for (int tl = 0; tl < 2; ++tl) {
        int qi = qis[tl];
        f32x4 O[2][4] = {};
        float mst[2][4], lst[2][4];
        #pragma unroll
        for (int mi = 0; mi < 2; ++mi)
            #pragma unroll
            for (int r = 0; r < 4; ++r) { mst[mi][r] = -INFINITY; lst[mi][r] = 0.f; }

        for (int st = 0; st <= qi; ++st) {
            int sb = st * 32;
            f32x4 S[2][2] = {};
            #pragma unroll
            for (int kc = 0; kc < 2; ++kc) {
                uint4 Kf[2];
                #pragma unroll
                for (int ji = 0; ji < 2; ++ji)
                    Kf[ji] = *(const uint4*)&Ks[(sb + ji*16 + ln)*72 + kc*32 + quad*8];
                __builtin_amdgcn_s_setprio(1);
                #pragma unroll
                for (int mi = 0; mi < 2; ++mi) {
                    bf16x8 qa = __builtin_bit_cast(bf16x8, Qf[tl][mi][kc]);
                    #pragma unroll
                    for (int ji = 0; ji < 2; ++ji)
                        S[mi][ji] = __builtin_amdgcn_mfma_f32_16x16x32_bf16(
                            qa, __builtin_bit_cast(bf16x8, Kf[ji]), S[mi][ji], 0, 0, 0);
                }
                __builtin_amdgcn_s_setprio(0);
            }
            int diag = (st == qi);
            #pragma unroll
            for (int mi = 0; mi < 2; ++mi)
                #pragma unroll
                for (int ji = 0; ji < 2; ++ji)
                    #pragma unroll
                    for (int r = 0; r < 4; ++r) {
                        float v = S[mi][ji][r] * scale;
                        if (diag && (ji*16 + ln) > (mi*16 + quad*4 + r)) v = -INFINITY;
                        S[mi][ji][r] = v;
                    }
            #pragma unroll
            for (int mi = 0; mi < 2; ++mi)
                #pragma unroll
                for (int r = 0; r < 4; ++r) {
                    float mx = fmaxf(S[mi][0][r], S[mi][1][r]);
                    #pragma unroll
                    for (int off = 1; off < 16; off <<= 1)
                        mx = fmaxf(mx, __shfl_xor(mx, off));
                    float mn = fmaxf(mst[mi][r], mx);
                    float al = __expf(mst[mi][r] - mn);
                    mst[mi][r] = mn;
                    float p0 = __expf(S[mi][0][r] - mn);
                    float p1 = __expf(S[mi][1][r] - mn);
                    S[mi][0][r] = p0; S[mi][1][r] = p1;
                    float rs = p0 + p1;
                    #pragma unroll
                    for (int off = 1; off < 16; off <<= 1)
                        rs += __shfl_xor(rs, off);
                    lst[mi][r] = lst[mi][r]*al + rs;
                    #pragma unroll
                    for (int ei = 0; ei < 4; ++ei) O[mi][ei][r] *= al;
                }
            #pragma unroll
            for (int mi = 0; mi < 2; ++mi)
                #pragma unroll
                for (int ji = 0; ji < 2; ++ji)
                    #pragma unroll
                    for (int r = 0; r < 4; ++r)
                        P[(mi*16 + quad*4 + r)*40 + ji*16 + ln] = (__bf16)S[mi][ji][r];
            uint4 Pf[2], Vf[4];
            #pragma unroll
            for (int mi = 0; mi < 2; ++mi)
                Pf[mi] = *(const uint4*)&P[(mi*16 + ln)*40 + quad*8];
            #pragma unroll
            for (int ei = 0; ei < 4; ++ei) {
                int e = ei*16 + ln;
                Vf[ei] = *(const uint4*)&Vt[e*264 + (((st*4 + quad) ^ ((e >> 3) & 3)) * 8)];
            }
            __builtin_amdgcn_s_setprio(1);
            #pragma unroll
            for (int mi = 0; mi < 2; ++mi)
                #pragma unroll
                for (int ei = 0; ei < 4; ++ei)
                    O[mi][ei] = __builtin_amdgcn_mfma_f32_16x16x32_bf16(
                        __builtin_bit_cast(bf16x8, Pf[mi]),
                        __builtin_bit_cast(bf16x8, Vf[ei]), O[mi][ei], 0, 0, 0);
            __builtin_amdgcn_s_setprio(0);
        }
        #pragma unroll
        for (int mi = 0; mi < 2; ++mi)
            #pragma unroll
            for (int r = 0; r < 4; ++r) {
                float inv = 1.0f / lst[mi][r];
                size_t row = (size_t)(b*T_ + qi*32 + mi*16 + quad*4 + r);
                #pragma unroll
                for (int ei = 0; ei < 4; ++ei)
                    o[row*D_ + hoff + ei*16 + ln] = (__bf16)(O[mi][ei][r] * inv);
            }
    }
}

// ---------------------------------------------------------------- loss
__global__ __launch_bounds__(256)
void loss2(const float* __restrict__ logits,
           const int* __restrict__ tg,
           float* __restrict__ loss)
{
    int t = threadIdx.x;
    int g16 = t >> 4, ln = t & 15;
    int row = blockIdx.x * 16 + g16;
    const float* lr = logits + (size_t)row * V_;
    float v0 = lr[ln], v1 = lr[16+ln], v2 = lr[32+ln], v3 = lr[48+ln];
    float v4 = (ln == 0) ? lr[64] : -INFINITY;
    float m = fmaxf(fmaxf(fmaxf(v0, v1), fmaxf(v2, v3)), v4);
    #pragma unroll
    for (int off = 1; off < 16; off <<= 1) m = fmaxf(m, __shfl_xor(m, off));
    float s = __expf(v0-m) + __expf(v1-m) + __expf(v2-m) + __expf(v3-m);
    if (ln == 0) s += __expf(v4-m);
    #pragma unroll
    for (int off = 1; off < 16; off <<= 1) s += __shfl_xor(s, off);
    float val = 0.f;
    if (ln == 0)
        val = -(lr[tg[row]] - m - __logf(s)) * (1.0f/ROWS);
    #pragma unroll
    for (int off = 16; off < 64; off <<= 1) val += __shfl_xor(val, off);
    __shared__ float red[4];
    int w = t >> 6;
    if ((t & 63) == 0) red[w] = val;
    __syncthreads();
    if (t == 0)
        atomicAdd(loss, red[0]+red[1]+red[2]+red[3]);
}

// ---------------------------------------------------------------- launch
extern "C" void kernel_launch(void* const* d_in, const int* in_sizes, int n_in,
                              void* d_out, int out_size, void* d_ws, size_t ws_size,
                              hipStream_t stream)
{
    const int*   idx     = (const int*)  d_in[0];
    const int*   targets = (const int*)  d_in[1];
    const float* tok     = (const float*)d_in[2];
    const float* pos     = (const float*)d_in[3];
    const float* Wq      = (const float*)d_in[4];
    const float* Wk      = (const float*)d_in[5];
    const float* Wv      = (const float*)d_in[6];
    const float* Wproj   = (const float*)d_in[7];
    const float* bproj   = (const float*)d_in[8];
    const float* W1      = (const float*)d_in[9];
    const float* b1      = (const float*)d_in[10];
    const float* W2      = (const float*)d_in[11];
    const float* b2      = (const float*)d_in[12];
    const float* ln1g    = (const float*)d_in[13];
    const float* ln1b    = (const float*)d_in[14];
    const float* lnfg    = (const float*)d_in[15];
    const float* lnfb    = (const float*)d_in[16];
    const float* Whead   = (const float*)d_in[17];
    const float* bhead   = (const float*)d_in[18];

    float* logits = (float*)d_out;
    float* loss   = logits + (size_t)ROWS * V_;

    const size_t SZ = (size_t)ROWS * D_;             // 6291456
    const size_t RGELEMS = (size_t)ROWS * 4 * D_;    // 25165824 bf16 elems

    float*  x   = (float*)d_ws;                      // SZ f32
    __bf16* yb  = (__bf16*)(x + SZ);                 // SZ bf16
    __bf16* Rg  = yb + SZ;                           // RGELEMS bf16 (qkv / hid)
    __bf16* qkv = Rg;                                // ROWS*1152
    __bf16* hid = Rg;                                // ROWS*1536
    __bf16* o   = Rg + RGELEMS;                      // SZ bf16
    __bf16* qkvT  = o + SZ;                          // L*1152*384
    __bf16* projT = qkvT + (size_t)L_*QKVN*D_;       // L*384*384
    __bf16* w1T   = projT + (size_t)L_*D_*D_;        // L*1536*384
    __bf16* w2T   = w1T + (size_t)L_*D_*4*D_;        // L*384*1536
    __bf16* headT = w2T + (size_t)L_*D_*4*D_;        // 128*384

    // weight conversion (transpose to [N][K] bf16)
    transpose_cast<<<dim3(2,12,36),256,0,stream>>>(Wq, qkvT, D_, HS_, H_,
        (long)QKVN*D_, (long)HS_*D_, 0L);
    transpose_cast<<<dim3(2,12,36),256,0,stream>>>(Wk, qkvT, D_, HS_, H_,
        (long)QKVN*D_, (long)HS_*D_, (long)D_*D_);
    transpose_cast<<<dim3(2,12,36),256,0,stream>>>(Wv, qkvT, D_, HS_, H_,
        (long)QKVN*D_, (long)HS_*D_, 2L*D_*D_);
    transpose_cast<<<dim3(12,12,6),256,0,stream>>>(Wproj, projT, D_, D_, 1,
        (long)D_*D_, 0L, 0L);
    transpose_cast<<<dim3(48,12,6),256,0,stream>>>(W1, w1T, D_, 4*D_, 1,
        (long)D_*4*D_, 0L, 0L);
    transpose_cast<<<dim3(12,48,6),256,0,stream>>>(W2, w2T, 4*D_, D_, 1,
        (long)D_*4*D_, 0L, 0L);
    head_prep<<<(128*D_)/256, 256, 0, stream>>>(Whead, headT);

    embed_kernel<<<(ROWS*D_/4)/256, 256, 0, stream>>>(idx, tok, pos, x);

    for (int l = 0; l < L_; ++l) {
        ln4<<<ROWS/4, 256, 0, stream>>>(x, ln1g + l*D_, ln1b + l*D_, yb);
        gemm128s<<<dim3(ROWS/128, QKVN/128), 256, 0, stream>>>(
            yb, qkvT + (size_t)l*QKVN*D_, nullptr, nullptr, qkv,
            D_, QKVN, QKVN, 0);
        attn4<<<B_*H_, 256, 0, stream>>>(qkv, o);
        gemm64s<<<dim3(ROWS/64, D_/128), 256, 0, stream>>>(
            o, projT + (size_t)l*D_*D_, bproj + l*D_, x, x, nullptr,
            D_, D_, D_, 0);
        ln4<<<ROWS/4, 256, 0, stream>>>(x, ln1g + l*D_, ln1b + l*D_, yb);
        gemm128s<<<dim3(ROWS/128, 4*D_/128), 256, 0, stream>>>(
            yb, w1T + (size_t)l*D_*4*D_, b1 + l*4*D_, nullptr, hid,
            D_, 4*D_, 4*D_, 1);
        gemm64s<<<dim3(ROWS/64, D_/128), 256, 0, stream>>>(
            hid, w2T + (size_t)l*D_*4*D_, b2 + l*D_, x, x, nullptr,
            4*D_, D_, D_, 0);
    }
    ln4<<<ROWS/4, 256, 0, stream>>>(x, lnfg, lnfb, yb);
    gemm64s<<<dim3(ROWS/64, 1), 256, 0, stream>>>(
        yb, headT, bhead, nullptr, logits, nullptr,
        D_, V_, V_, 0);
    hipMemsetAsync(loss, 0, sizeof(float), stream);
    loss2<<<ROWS/16, 256, 0, stream>>>(logits, targets, loss);
}